// Round 1
// baseline (3551.601 us; speedup 1.0000x reference)
//
#include <hip/hip_runtime.h>
#include <math.h>

#define BB 16
#define TT 360
#define VV 25
#define NN 9000
#define EE 72000
#define HH 128
#define NCLSS 12
#define EPSB 1e-5f

// ---------------- graph preprocessing ----------------

__global__ void k_count(const int* __restrict__ ei, int* __restrict__ counts) {
    int e = blockIdx.x * 256 + threadIdx.x;
    if (e < EE) atomicAdd(&counts[ei[EE + e]], 1);
}

__global__ void k_dinv(const int* __restrict__ counts, float* __restrict__ dinv) {
    int n = blockIdx.x * 256 + threadIdx.x;
    if (n < NN) dinv[n] = rsqrtf((float)(counts[n] + 1));  // +1 self-loop
}

__global__ void k_scan(const int* __restrict__ counts, int* __restrict__ rowptr) {
    __shared__ int part[1024];
    int t = threadIdx.x;
    int base = t * 9;
    int loc[9];
    int s = 0;
#pragma unroll
    for (int i = 0; i < 9; i++) {
        int idx = base + i;
        int v = (idx < NN) ? counts[idx] : 0;
        loc[i] = s;
        s += v;
    }
    part[t] = s;
    __syncthreads();
    for (int d = 1; d < 1024; d <<= 1) {
        int v = (t >= d) ? part[t - d] : 0;
        __syncthreads();
        part[t] += v;
        __syncthreads();
    }
    int excl = (t == 0) ? 0 : part[t - 1];
#pragma unroll
    for (int i = 0; i < 9; i++) {
        int idx = base + i;
        if (idx < NN) rowptr[idx] = excl + loc[i];
    }
    if (t == 1023) rowptr[NN] = part[1023];
}

__global__ void k_fill(const int* __restrict__ ei, const int* __restrict__ rowptr,
                       int* __restrict__ cursor, const float* __restrict__ dinv,
                       int* __restrict__ csr_src, float* __restrict__ csr_coef) {
    int e = blockIdx.x * 256 + threadIdx.x;
    if (e >= EE) return;
    int s = ei[e], d = ei[EE + e];
    int slot = rowptr[d] + atomicAdd(&cursor[d], 1);
    csr_src[slot] = s;
    csr_coef[slot] = dinv[s] * dinv[d];
}

// ---------------- propagation (A_hat * h), with optional cyclic node shift ----------------

// 128 channels: one block per dst node, 128 threads = channels, 16 batch accumulators
__global__ void __launch_bounds__(128) k_prop(const float* __restrict__ h, float* __restrict__ P,
                                              const int* __restrict__ rowptr,
                                              const int* __restrict__ csr_src,
                                              const float* __restrict__ coef,
                                              const float* __restrict__ dinv, int shift) {
    int n = blockIdx.x;
    int c = threadIdx.x;
    int pn = n + shift;
    if (pn >= NN) pn -= NN;
    float d2 = dinv[n] * dinv[n];
    float acc[BB];
#pragma unroll
    for (int b = 0; b < BB; b++) acc[b] = d2 * h[(b * NN + pn) * HH + c];
    int beg = rowptr[n], end = rowptr[n + 1];
    for (int j = beg; j < end; j++) {
        int s = csr_src[j];
        float cf = coef[j];
        int ps = s + shift;
        if (ps >= NN) ps -= NN;
        const float* hp = h + ps * HH + c;
#pragma unroll
        for (int b = 0; b < BB; b++) acc[b] += cf * hp[b * NN * HH];
    }
#pragma unroll
    for (int b = 0; b < BB; b++) P[(b * NN + n) * HH + c] = acc[b];
}

// 2-channel version for the input layer (propagate x before the 2->128 matmul)
__global__ void k_prop2(const float* __restrict__ x, float* __restrict__ P0,
                        const int* __restrict__ rowptr, const int* __restrict__ csr_src,
                        const float* __restrict__ coef, const float* __restrict__ dinv) {
    int n = blockIdx.x * 256 + threadIdx.x;
    if (n >= NN) return;
    int b = blockIdx.y;
    const float* xb = x + b * NN * 2;
    float d2 = dinv[n] * dinv[n];
    float a0 = d2 * xb[2 * n], a1 = d2 * xb[2 * n + 1];
    int beg = rowptr[n], end = rowptr[n + 1];
    for (int j = beg; j < end; j++) {
        int s = csr_src[j];
        float cf = coef[j];
        a0 += cf * xb[2 * s];
        a1 += cf * xb[2 * s + 1];
    }
    float* Pb = P0 + (b * NN + n) * 2;
    Pb[0] = a0;
    Pb[1] = a1;
}

// ---------------- matmul (P * W + bias), in-place capable ----------------

template <int K>
__global__ void __launch_bounds__(256) k_matmul(const float* Pin, float* Aout,
                                                const float* __restrict__ W,
                                                const float* __restrict__ bias) {
    __shared__ float p[16][K];
    int row0 = blockIdx.x * 16;
    int t = threadIdx.x;
    for (int i = t; i < 16 * K; i += 256) p[i / K][i % K] = Pin[row0 * K + i];
    __syncthreads();
    int c = t & (HH - 1);
    int rg = t >> 7;  // 0 or 1: rows rg*8 .. rg*8+7
    float acc[8];
#pragma unroll
    for (int r = 0; r < 8; r++) acc[r] = 0.f;
#pragma unroll 4
    for (int k = 0; k < K; k++) {
        float w = W[k * HH + c];
#pragma unroll
        for (int r = 0; r < 8; r++) acc[r] += p[rg * 8 + r][k] * w;
    }
    float bb = bias[c];
#pragma unroll
    for (int r = 0; r < 8; r++) Aout[(row0 + rg * 8 + r) * HH + c] = acc[r] + bb;
}

// ---------------- BN statistics ----------------

__global__ void __launch_bounds__(256) k_stats(const float* __restrict__ A,
                                               float* __restrict__ ssum, float* __restrict__ ssq) {
    __shared__ float l1[256], l2[256];
    int t = threadIdx.x;
    int c = t & 127, rg = t >> 7;
    int r0 = blockIdx.x * 500;
    float s1 = 0.f, s2 = 0.f;
    for (int r = r0 + rg; r < r0 + 500; r += 2) {
        float v = A[r * HH + c];
        s1 += v;
        s2 += v * v;
    }
    l1[t] = s1;
    l2[t] = s2;
    __syncthreads();
    if (rg == 0) {
        s1 += l1[t + 128];
        s2 += l2[t + 128];
        atomicAdd(&ssum[c], s1);
        atomicAdd(&ssq[c], s2);
    }
}

__global__ void k_bnfin(const float* __restrict__ ssum, const float* __restrict__ ssq,
                        const float* __restrict__ g, const float* __restrict__ be,
                        float* __restrict__ scale, float* __restrict__ shiftv) {
    int c = threadIdx.x;
    float inv = 1.0f / (BB * NN);
    float mu = ssum[c] * inv;
    float var = ssq[c] * inv - mu * mu;
    float sc = g[c] * rsqrtf(var + EPSB);
    scale[c] = sc;
    shiftv[c] = be[c] - mu * sc;
}

__global__ void k_bnrelu(float* __restrict__ A, const float* __restrict__ scale,
                         const float* __restrict__ shiftv) {
    int i = blockIdx.x * 256 + threadIdx.x;
    int c = i & 127;
    float v = A[i] * scale[c] + shiftv[c];
    A[i] = v > 0.f ? v : 0.f;
}

// ---------------- head: fused BN+ReLU+mean-pool, then linear+log_softmax ----------------

__global__ void k_relu_pool(const float* __restrict__ A, const float* __restrict__ scale,
                            const float* __restrict__ shiftv, float* __restrict__ pooled) {
    int c = threadIdx.x;
    int b = blockIdx.y;
    int n0 = blockIdx.x * 250;
    float sc = scale[c], sh = shiftv[c];
    float acc = 0.f;
    const float* Ab = A + (b * NN + n0) * HH + c;
    for (int n = 0; n < 250; n++) {
        float v = Ab[n * HH] * sc + sh;
        acc += v > 0.f ? v : 0.f;
    }
    atomicAdd(&pooled[b * HH + c], acc);
}

__global__ void __launch_bounds__(192) k_head(const float* __restrict__ pooled,
                                              const float* __restrict__ Wf,
                                              const float* __restrict__ bf,
                                              float* __restrict__ outp, int bstride) {
    __shared__ float z[BB][NCLSS];
    __shared__ float lse[BB];
    int t = threadIdx.x;
    int b = t / NCLSS, j = t % NCLSS;
    if (t < BB * NCLSS) {
        float acc = bf[j];
        const float* pb = pooled + b * HH;
        const float invn = 1.0f / NN;
        for (int c = 0; c < HH; c++) acc += pb[c] * invn * Wf[c * NCLSS + j];
        z[b][j] = acc;
    }
    __syncthreads();
    if (t < BB) {
        float m = -1e30f;
        for (int j2 = 0; j2 < NCLSS; j2++) m = fmaxf(m, z[t][j2]);
        float s = 0.f;
        for (int j2 = 0; j2 < NCLSS; j2++) s += expf(z[t][j2] - m);
        lse[t] = m + logf(s);
    }
    __syncthreads();
    if (t < BB * NCLSS) outp[b * bstride + j] = z[b][j] - lse[b];
}

// ---------------- host ----------------

extern "C" void kernel_launch(void* const* d_in, const int* in_sizes, int n_in, void* d_out,
                              int out_size, void* d_ws, size_t ws_size, hipStream_t stream) {
    const float* x = (const float*)d_in[0];
    const int* ei = (const int*)d_in[1];
    const float* W_in = (const float*)d_in[2];
    const float* b_in = (const float*)d_in[3];
    const float* g_in = (const float*)d_in[4];
    const float* be_in = (const float*)d_in[5];
    const float* shared_W = (const float*)d_in[6];
    const float* shared_b = (const float*)d_in[7];
    const float* shared_g = (const float*)d_in[8];
    const float* shared_be = (const float*)d_in[9];
    const float* main_Wg = (const float*)d_in[10];
    const float* main_bg = (const float*)d_in[11];
    const float* main_g = (const float*)d_in[12];
    const float* main_be = (const float*)d_in[13];
    const float* main_Wf = (const float*)d_in[14];
    const float* main_bf = (const float*)d_in[15];
    const float* aux_Wg = (const float*)d_in[16];
    const float* aux_bg = (const float*)d_in[17];
    const float* aux_g = (const float*)d_in[18];
    const float* aux_be = (const float*)d_in[19];
    const float* aux_Wf = (const float*)d_in[20];
    const float* aux_bf = (const float*)d_in[21];
    float* out = (float*)d_out;

    char* w = (char*)d_ws;
    float* X = (float*)w;      w += (size_t)BB * NN * HH * 4;
    float* Y = (float*)w;      w += (size_t)BB * NN * HH * 4;
    float* P0 = (float*)w;     w += (size_t)BB * NN * 2 * 4;
    int* counts = (int*)w;     w += NN * 4;
    int* cursor = (int*)w;     w += NN * 4;
    int* rowptr = (int*)w;     w += (NN + 1) * 4;
    int* csr_src = (int*)w;    w += EE * 4;
    float* csr_coef = (float*)w; w += EE * 4;
    float* dinv = (float*)w;   w += NN * 4;
    float* ssum = (float*)w;   w += HH * 4;
    float* ssq = (float*)w;    w += HH * 4;
    float* scale = (float*)w;  w += HH * 4;
    float* shiftv = (float*)w; w += HH * 4;
    float* pooled = (float*)w; w += BB * HH * 4;

    // graph prep
    hipMemsetAsync(counts, 0, 2 * NN * 4, stream);  // counts + cursor (contiguous)
    k_count<<<(EE + 255) / 256, 256, 0, stream>>>(ei, counts);
    k_dinv<<<(NN + 255) / 256, 256, 0, stream>>>(counts, dinv);
    k_scan<<<1, 1024, 0, stream>>>(counts, rowptr);
    k_fill<<<(EE + 255) / 256, 256, 0, stream>>>(ei, rowptr, cursor, dinv, csr_src, csr_coef);

    // L0: din=2
    {
        dim3 g((NN + 255) / 256, BB);
        k_prop2<<<g, 256, 0, stream>>>(x, P0, rowptr, csr_src, csr_coef, dinv);
        hipMemsetAsync(ssum, 0, 2 * HH * 4, stream);  // ssum + ssq (contiguous)
        k_matmul<2><<<BB * NN / 16, 256, 0, stream>>>(P0, X, W_in, b_in);
        k_stats<<<288, 256, 0, stream>>>(X, ssum, ssq);
        k_bnfin<<<1, HH, 0, stream>>>(ssum, ssq, g_in, be_in, scale, shiftv);
        k_bnrelu<<<BB * NN * HH / 256, 256, 0, stream>>>(X, scale, shiftv);
    }

    // shared layers
    float* hcur = X;
    float* other = Y;
    for (int l = 0; l < 2; l++) {
        k_prop<<<NN, 128, 0, stream>>>(hcur, other, rowptr, csr_src, csr_coef, dinv, 0);
        hipMemsetAsync(ssum, 0, 2 * HH * 4, stream);
        k_matmul<HH><<<BB * NN / 16, 256, 0, stream>>>(other, other, shared_W + l * HH * HH,
                                                       shared_b + l * HH);
        k_stats<<<288, 256, 0, stream>>>(other, ssum, ssq);
        k_bnfin<<<1, HH, 0, stream>>>(ssum, ssq, shared_g + l * HH, shared_be + l * HH, scale,
                                      shiftv);
        k_bnrelu<<<BB * NN * HH / 256, 256, 0, stream>>>(other, scale, shiftv);
        float* tmp = hcur;
        hcur = other;
        other = tmp;
    }

    // heads: hd=0 main (shift 0), hd=1..8 aux (node shift = hd*ws*V = hd*1000)
    for (int hd = 0; hd < 9; hd++) {
        int shift = hd * (TT / 9) * VV;
        const float* Wg = (hd == 0) ? main_Wg : aux_Wg + (hd - 1) * HH * HH;
        const float* bg = (hd == 0) ? main_bg : aux_bg + (hd - 1) * HH;
        const float* gg = (hd == 0) ? main_g : aux_g + (hd - 1) * HH;
        const float* be = (hd == 0) ? main_be : aux_be + (hd - 1) * HH;
        const float* Wf = (hd == 0) ? main_Wf : aux_Wf + (hd - 1) * HH * NCLSS;
        const float* bf = (hd == 0) ? main_bf : aux_bf + (hd - 1) * NCLSS;
        float* outp = (hd == 0) ? out : out + BB * NCLSS + (hd - 1) * NCLSS;
        int bstride = (hd == 0) ? NCLSS : 8 * NCLSS;

        k_prop<<<NN, 128, 0, stream>>>(hcur, other, rowptr, csr_src, csr_coef, dinv, shift);
        hipMemsetAsync(ssum, 0, 2 * HH * 4, stream);
        k_matmul<HH><<<BB * NN / 16, 256, 0, stream>>>(other, other, Wg, bg);
        k_stats<<<288, 256, 0, stream>>>(other, ssum, ssq);
        k_bnfin<<<1, HH, 0, stream>>>(ssum, ssq, gg, be, scale, shiftv);
        hipMemsetAsync(pooled, 0, BB * HH * 4, stream);
        dim3 gp(36, BB);
        k_relu_pool<<<gp, 128, 0, stream>>>(other, scale, shiftv, pooled);
        k_head<<<1, 192, 0, stream>>>(pooled, Wf, bf, outp, bstride);
    }
}

// Round 2
// 2297.521 us; speedup vs baseline: 1.5458x; 1.5458x over previous
//
#include <hip/hip_runtime.h>
#include <hip/hip_bf16.h>
#include <math.h>

#define BB 16
#define TT 360
#define VV 25
#define NN 9000
#define EE 72000
#define HH 128
#define RR (NN * BB)  // 144000 rows, node-major: row = n*BB + b
#define NCLSS 12
#define EPSB 1e-5f

typedef short short8 __attribute__((ext_vector_type(8)));
typedef float float16v __attribute__((ext_vector_type(16)));
typedef unsigned short ushort_t;

__device__ __forceinline__ float bf2f(ushort_t u) {
    union { unsigned i; float f; } w;
    w.i = ((unsigned)u) << 16;
    return w.f;
}
__device__ __forceinline__ ushort_t f2bf(float f) {
    union { float f; unsigned i; } w;
    w.f = f;
    unsigned r = (w.i + 0x7FFF + ((w.i >> 16) & 1)) >> 16;  // RNE
    return (ushort_t)r;
}

// ---------------- graph preprocessing ----------------

__global__ void k_count(const int* __restrict__ ei, int* __restrict__ counts) {
    int e = blockIdx.x * 256 + threadIdx.x;
    if (e < EE) atomicAdd(&counts[ei[EE + e]], 1);
}

__global__ void k_dinv(const int* __restrict__ counts, float* __restrict__ dinv) {
    int n = blockIdx.x * 256 + threadIdx.x;
    if (n < NN) dinv[n] = rsqrtf((float)(counts[n] + 1));
}

__global__ void k_scan(const int* __restrict__ counts, int* __restrict__ rowptr) {
    __shared__ int part[1024];
    int t = threadIdx.x;
    int base = t * 9;
    int loc[9];
    int s = 0;
#pragma unroll
    for (int i = 0; i < 9; i++) {
        int idx = base + i;
        int v = (idx < NN) ? counts[idx] : 0;
        loc[i] = s;
        s += v;
    }
    part[t] = s;
    __syncthreads();
    for (int d = 1; d < 1024; d <<= 1) {
        int v = (t >= d) ? part[t - d] : 0;
        __syncthreads();
        part[t] += v;
        __syncthreads();
    }
    int excl = (t == 0) ? 0 : part[t - 1];
#pragma unroll
    for (int i = 0; i < 9; i++) {
        int idx = base + i;
        if (idx < NN) rowptr[idx] = excl + loc[i];
    }
    if (t == 1023) rowptr[NN] = part[1023];
}

__global__ void k_fill(const int* __restrict__ ei, const int* __restrict__ rowptr,
                       int* __restrict__ cursor, const float* __restrict__ dinv,
                       int* __restrict__ csr_src, float* __restrict__ csr_coef) {
    int e = blockIdx.x * 256 + threadIdx.x;
    if (e >= EE) return;
    int s = ei[e], d = ei[EE + e];
    int slot = rowptr[d] + atomicAdd(&cursor[d], 1);
    csr_src[slot] = s;
    csr_coef[slot] = dinv[s] * dinv[d];
}

// ---------------- L0 propagation of raw x (2 channels) ----------------
// x is [B][N][2] batch-major; write P0 node-major [n*BB+b][2] fp32
__global__ void k_prop2(const float* __restrict__ x, float* __restrict__ P0,
                        const int* __restrict__ rowptr, const int* __restrict__ csr_src,
                        const float* __restrict__ coef, const float* __restrict__ dinv) {
    int n = blockIdx.x * 256 + threadIdx.x;
    if (n >= NN) return;
    int b = blockIdx.y;
    const float* xb = x + (size_t)b * NN * 2;
    float d2 = dinv[n] * dinv[n];
    float a0 = d2 * xb[2 * n], a1 = d2 * xb[2 * n + 1];
    int beg = rowptr[n], end = rowptr[n + 1];
    for (int j = beg; j < end; j++) {
        int s = csr_src[j];
        float cf = coef[j];
        a0 += cf * xb[2 * s];
        a1 += cf * xb[2 * s + 1];
    }
    float* Pb = P0 + (size_t)(n * BB + b) * 2;
    Pb[0] = a0;
    Pb[1] = a1;
}

// L0 matmul: A = P0 * W_in + b_in  (K=2), bf16 out
__global__ void k_mm2(const float* __restrict__ P0, ushort_t* __restrict__ A,
                      const float* __restrict__ W, const float* __restrict__ bias) {
    int i = blockIdx.x * 256 + threadIdx.x;  // over RR*16
    int r = i >> 4, c8 = (i & 15) * 8;
    float p0 = P0[2 * (size_t)r], p1 = P0[2 * (size_t)r + 1];
    short8 o;
#pragma unroll
    for (int j = 0; j < 8; j++) {
        float v = p0 * W[c8 + j] + p1 * W[HH + c8 + j] + bias[c8 + j];
        o[j] = (short)f2bf(v);
    }
    *(short8*)(A + (size_t)r * HH + c8) = o;
}

// ---------------- fused BN-affine + ReLU + propagation ----------------
// input h: pre-BN bf16 node-major; apply relu(h*sc+sh) on the fly while gathering.
__global__ void __launch_bounds__(256) k_prop(const ushort_t* __restrict__ h,
                                              ushort_t* __restrict__ P,
                                              const int* __restrict__ rowptr,
                                              const int* __restrict__ csr_src,
                                              const float* __restrict__ coef,
                                              const float* __restrict__ dinv,
                                              const float* __restrict__ scale,
                                              const float* __restrict__ shiftv, int shn) {
    int n = blockIdx.x;
    int t = threadIdx.x;
    int b = t >> 4, coff = (t & 15) * 8;
    float sc[8], sh[8];
#pragma unroll
    for (int j = 0; j < 8; j++) {
        sc[j] = scale[coff + j];
        sh[j] = shiftv[coff + j];
    }
    float acc[8];
    int pn = n + shn;
    if (pn >= NN) pn -= NN;
    float d2 = dinv[n] * dinv[n];
    {
        short8 v = *(const short8*)(h + (size_t)(pn * BB + b) * HH + coff);
#pragma unroll
        for (int j = 0; j < 8; j++) {
            float f = bf2f((ushort_t)v[j]) * sc[j] + sh[j];
            acc[j] = d2 * fmaxf(f, 0.f);
        }
    }
    int beg = rowptr[n], end = rowptr[n + 1];
    for (int e = beg; e < end; e++) {
        int s = csr_src[e];
        float cf = coef[e];
        int ps = s + shn;
        if (ps >= NN) ps -= NN;
        short8 v = *(const short8*)(h + (size_t)(ps * BB + b) * HH + coff);
#pragma unroll
        for (int j = 0; j < 8; j++) {
            float f = bf2f((ushort_t)v[j]) * sc[j] + sh[j];
            acc[j] += cf * fmaxf(f, 0.f);
        }
    }
    short8 o;
#pragma unroll
    for (int j = 0; j < 8; j++) o[j] = (short)f2bf(acc[j]);
    *(short8*)(P + (size_t)(n * BB + b) * HH + coff) = o;
}

// ---------------- MFMA bf16 matmul: A[RR x 128] = P[RR x 128] * W[128 x 128] + bias ----
// block: 256 thr (4 waves), tile 128 rows x 128 cols; W^T staged in LDS (swizzled).
__global__ void __launch_bounds__(256) k_mfma(const ushort_t* __restrict__ P,
                                              ushort_t* __restrict__ A,
                                              const float* __restrict__ W,
                                              const float* __restrict__ bias) {
    __shared__ ushort_t wt[128 * 128];  // wt[c][k], chunk-XOR-swizzled, 32KB
    int t = threadIdx.x;
    for (int i = t; i < 16384; i += 256) {
        int k = i & 127, c = i >> 7;
        int chunk = (k >> 3) ^ (c & 15);
        wt[c * 128 + chunk * 8 + (k & 7)] = f2bf(W[(size_t)k * HH + c]);
    }
    __syncthreads();
    int w = t >> 6, l = t & 63;
    int r0 = blockIdx.x * 128 + (w >> 1) * 64;
    int cb = (w & 1) * 64;
    int lr = l & 31, hi = l >> 5;
    float16v acc[2][2];
#pragma unroll
    for (int rt = 0; rt < 2; rt++)
#pragma unroll
        for (int ct = 0; ct < 2; ct++) acc[rt][ct] = (float16v)(0.0f);
#pragma unroll
    for (int ks = 0; ks < 8; ks++) {
        int koff = ks * 16 + hi * 8;
        short8 a0 = *(const short8*)(P + (size_t)(r0 + lr) * HH + koff);
        short8 a1 = *(const short8*)(P + (size_t)(r0 + 32 + lr) * HH + koff);
#pragma unroll
        for (int ct = 0; ct < 2; ct++) {
            int c = cb + ct * 32 + lr;
            int chunk = (ks * 2 + hi) ^ (c & 15);
            short8 bf = *(const short8*)(wt + c * 128 + chunk * 8);
            acc[0][ct] = __builtin_amdgcn_mfma_f32_32x32x16_bf16(a0, bf, acc[0][ct], 0, 0, 0);
            acc[1][ct] = __builtin_amdgcn_mfma_f32_32x32x16_bf16(a1, bf, acc[1][ct], 0, 0, 0);
        }
    }
#pragma unroll
    for (int rt = 0; rt < 2; rt++)
#pragma unroll
        for (int ct = 0; ct < 2; ct++) {
            int c = cb + ct * 32 + lr;
            float bv = bias[c];
#pragma unroll
            for (int g = 0; g < 16; g++) {
                int row = r0 + rt * 32 + (g & 3) + 8 * (g >> 2) + 4 * hi;
                A[(size_t)row * HH + c] = f2bf(acc[rt][ct][g] + bv);
            }
        }
}

// ---------------- BN statistics over bf16 A ----------------

__global__ void __launch_bounds__(256) k_stats(const ushort_t* __restrict__ A,
                                               float* __restrict__ ssum, float* __restrict__ ssq) {
    __shared__ float Ls1[256][8], Ls2[256][8];
    int t = threadIdx.x;
    int rg = t >> 4, c8 = (t & 15) * 8;
    int r0 = blockIdx.x * 500;
    float s1[8], s2[8];
#pragma unroll
    for (int j = 0; j < 8; j++) { s1[j] = 0.f; s2[j] = 0.f; }
    for (int r = r0 + rg; r < r0 + 500; r += 16) {
        short8 v = *(const short8*)(A + (size_t)r * HH + c8);
#pragma unroll
        for (int j = 0; j < 8; j++) {
            float f = bf2f((ushort_t)v[j]);
            s1[j] += f;
            s2[j] += f * f;
        }
    }
#pragma unroll
    for (int j = 0; j < 8; j++) { Ls1[t][j] = s1[j]; Ls2[t][j] = s2[j]; }
    __syncthreads();
    if (rg == 0) {  // t in 0..15, owns channels t*8..t*8+8
#pragma unroll
        for (int g = 1; g < 16; g++)
#pragma unroll
            for (int j = 0; j < 8; j++) {
                s1[j] += Ls1[t + 16 * g][j];
                s2[j] += Ls2[t + 16 * g][j];
            }
#pragma unroll
        for (int j = 0; j < 8; j++) {
            atomicAdd(&ssum[t * 8 + j], s1[j]);
            atomicAdd(&ssq[t * 8 + j], s2[j]);
        }
    }
}

// finalize BN affine; then re-zero ssum/ssq for the next layer's stats
__global__ void k_bnfin(float* __restrict__ ssum, float* __restrict__ ssq,
                        const float* __restrict__ g, const float* __restrict__ be,
                        float* __restrict__ scale, float* __restrict__ shiftv) {
    int c = threadIdx.x;
    float inv = 1.0f / (float)RR;
    float mu = ssum[c] * inv;
    float var = ssq[c] * inv - mu * mu;
    float sc = g[c] * rsqrtf(var + EPSB);
    scale[c] = sc;
    shiftv[c] = be[c] - mu * sc;
    ssum[c] = 0.f;
    ssq[c] = 0.f;
}

// fused BN-affine + ReLU + mean-pool (per head)
__global__ void __launch_bounds__(256) k_relu_pool(const ushort_t* __restrict__ A,
                                                   const float* __restrict__ scale,
                                                   const float* __restrict__ shiftv,
                                                   float* __restrict__ pooled) {
    __shared__ float L[256][8];
    int t = threadIdx.x;
    int b = blockIdx.y;
    int n0 = blockIdx.x * 250;
    int ng = t >> 4, c8 = (t & 15) * 8;
    float sc[8], sh[8];
#pragma unroll
    for (int j = 0; j < 8; j++) {
        sc[j] = scale[c8 + j];
        sh[j] = shiftv[c8 + j];
    }
    float acc[8];
#pragma unroll
    for (int j = 0; j < 8; j++) acc[j] = 0.f;
    for (int n = n0 + ng; n < n0 + 250; n += 16) {
        short8 v = *(const short8*)(A + (size_t)(n * BB + b) * HH + c8);
#pragma unroll
        for (int j = 0; j < 8; j++) {
            float f = bf2f((ushort_t)v[j]) * sc[j] + sh[j];
            acc[j] += fmaxf(f, 0.f);
        }
    }
#pragma unroll
    for (int j = 0; j < 8; j++) L[t][j] = acc[j];
    __syncthreads();
    if (ng == 0) {
#pragma unroll
        for (int g = 1; g < 16; g++)
#pragma unroll
            for (int j = 0; j < 8; j++) acc[j] += L[t + 16 * g][j];
#pragma unroll
        for (int j = 0; j < 8; j++) atomicAdd(&pooled[b * HH + t * 8 + j], acc[j]);
    }
}

// all 9 heads: linear + log_softmax
__global__ void __launch_bounds__(192) k_head_all(const float* __restrict__ pooled,
                                                  const float* __restrict__ main_Wf,
                                                  const float* __restrict__ main_bf,
                                                  const float* __restrict__ aux_Wf,
                                                  const float* __restrict__ aux_bf,
                                                  float* __restrict__ out) {
    int hd = blockIdx.x;
    const float* Wf = hd ? aux_Wf + (size_t)(hd - 1) * HH * NCLSS : main_Wf;
    const float* bf = hd ? aux_bf + (hd - 1) * NCLSS : main_bf;
    const float* pl = pooled + (size_t)hd * BB * HH;
    __shared__ float z[BB][NCLSS];
    __shared__ float lse[BB];
    int t = threadIdx.x;
    int b = t / NCLSS, j = t % NCLSS;
    if (t < BB * NCLSS) {
        float acc = bf[j];
        const float invn = 1.0f / NN;
        for (int c = 0; c < HH; c++) acc += pl[b * HH + c] * invn * Wf[c * NCLSS + j];
        z[b][j] = acc;
    }
    __syncthreads();
    if (t < BB) {
        float m = -1e30f;
        for (int j2 = 0; j2 < NCLSS; j2++) m = fmaxf(m, z[t][j2]);
        float s = 0.f;
        for (int j2 = 0; j2 < NCLSS; j2++) s += expf(z[t][j2] - m);
        lse[t] = m + logf(s);
    }
    __syncthreads();
    if (t < BB * NCLSS) {
        float* o = hd ? out + BB * NCLSS + ((size_t)b * 8 + (hd - 1)) * NCLSS + j
                      : out + b * NCLSS + j;
        *o = z[b][j] - lse[b];
    }
}

// ---------------- host ----------------

extern "C" void kernel_launch(void* const* d_in, const int* in_sizes, int n_in, void* d_out,
                              int out_size, void* d_ws, size_t ws_size, hipStream_t stream) {
    const float* x = (const float*)d_in[0];
    const int* ei = (const int*)d_in[1];
    const float* W_in = (const float*)d_in[2];
    const float* b_in = (const float*)d_in[3];
    const float* g_in = (const float*)d_in[4];
    const float* be_in = (const float*)d_in[5];
    const float* shared_W = (const float*)d_in[6];
    const float* shared_b = (const float*)d_in[7];
    const float* shared_g = (const float*)d_in[8];
    const float* shared_be = (const float*)d_in[9];
    const float* main_Wg = (const float*)d_in[10];
    const float* main_bg = (const float*)d_in[11];
    const float* main_g = (const float*)d_in[12];
    const float* main_be = (const float*)d_in[13];
    const float* main_Wf = (const float*)d_in[14];
    const float* main_bf = (const float*)d_in[15];
    const float* aux_Wg = (const float*)d_in[16];
    const float* aux_bg = (const float*)d_in[17];
    const float* aux_g = (const float*)d_in[18];
    const float* aux_be = (const float*)d_in[19];
    const float* aux_Wf = (const float*)d_in[20];
    const float* aux_bf = (const float*)d_in[21];
    float* out = (float*)d_out;

    char* w = (char*)d_ws;
    const size_t BIG = (size_t)RR * HH * 2;  // 36,864,000 bytes
    ushort_t* U = (ushort_t*)w; w += BIG;
    ushort_t* V = (ushort_t*)w; w += BIG;
    ushort_t* P = (ushort_t*)w; w += BIG;
    float* P0 = (float*)w;      w += (size_t)RR * 2 * 4;
    int* csr_src = (int*)w;     w += EE * 4;
    float* csr_coef = (float*)w; w += EE * 4;
    int* counts = (int*)w;      w += NN * 4;
    int* cursor = (int*)w;      w += NN * 4;
    float* dinv = (float*)w;    w += NN * 4;
    int* rowptr = (int*)w;      w += 36016;  // (NN+1)*4 padded to 16B
    float* ssum = (float*)w;    w += 512;
    float* ssq = (float*)w;     w += 512;
    float* pooled = (float*)w;  w += 9 * BB * HH * 4;  // 73728
    float* tscale = (float*)w;  w += 512;
    float* tshift = (float*)w;  w += 512;
    float* hscale = (float*)w;  w += 512;
    float* hshift = (float*)w;  w += 512;

    // zero: counts+cursor (contiguous), and ssum+ssq+pooled (contiguous)
    hipMemsetAsync(counts, 0, 2 * NN * 4, stream);
    hipMemsetAsync(ssum, 0, 512 + 512 + 9 * BB * HH * 4, stream);

    // graph prep
    k_count<<<(EE + 255) / 256, 256, 0, stream>>>(ei, counts);
    k_dinv<<<(NN + 255) / 256, 256, 0, stream>>>(counts, dinv);
    k_scan<<<1, 1024, 0, stream>>>(counts, rowptr);
    k_fill<<<(EE + 255) / 256, 256, 0, stream>>>(ei, rowptr, cursor, dinv, csr_src, csr_coef);

    // L0: prop raw x (2ch), then K=2 matmul -> U (pre-BN bf16)
    {
        dim3 g((NN + 255) / 256, BB);
        k_prop2<<<g, 256, 0, stream>>>(x, P0, rowptr, csr_src, csr_coef, dinv);
        k_mm2<<<RR * 16 / 256, 256, 0, stream>>>(P0, U, W_in, b_in);
        k_stats<<<288, 256, 0, stream>>>(U, ssum, ssq);
        k_bnfin<<<1, HH, 0, stream>>>(ssum, ssq, g_in, be_in, tscale, tshift);
    }

    // shared trunk layers: U -> V -> U  (A buffers hold pre-BN values)
    ushort_t* hcur = U;
    ushort_t* hnext = V;
    for (int l = 0; l < 2; l++) {
        k_prop<<<NN, 256, 0, stream>>>(hcur, P, rowptr, csr_src, csr_coef, dinv, tscale, tshift, 0);
        k_mfma<<<RR / 128, 256, 0, stream>>>(P, hnext, shared_W + (size_t)l * HH * HH,
                                             shared_b + l * HH);
        k_stats<<<288, 256, 0, stream>>>(hnext, ssum, ssq);
        k_bnfin<<<1, HH, 0, stream>>>(ssum, ssq, shared_g + l * HH, shared_be + l * HH, tscale,
                                      tshift);
        ushort_t* tmp = hcur; hcur = hnext; hnext = tmp;
    }
    // trunk output: hcur (= U), with affine tscale/tshift

    // heads: hd=0 main, hd=1..8 aux with node shift hd*1000
    for (int hd = 0; hd < 9; hd++) {
        int shift = hd * (TT / (NCLSS - 3)) * VV;  // hd * 40 * 25 = hd*1000
        const float* Wg = (hd == 0) ? main_Wg : aux_Wg + (size_t)(hd - 1) * HH * HH;
        const float* bg = (hd == 0) ? main_bg : aux_bg + (hd - 1) * HH;
        const float* gg = (hd == 0) ? main_g : aux_g + (hd - 1) * HH;
        const float* be = (hd == 0) ? main_be : aux_be + (hd - 1) * HH;

        k_prop<<<NN, 256, 0, stream>>>(hcur, P, rowptr, csr_src, csr_coef, dinv, tscale, tshift,
                                       shift);
        k_mfma<<<RR / 128, 256, 0, stream>>>(P, hnext, Wg, bg);
        k_stats<<<288, 256, 0, stream>>>(hnext, ssum, ssq);
        k_bnfin<<<1, HH, 0, stream>>>(ssum, ssq, gg, be, hscale, hshift);
        dim3 gp(36, BB);
        k_relu_pool<<<gp, 256, 0, stream>>>(hnext, hscale, hshift, pooled + (size_t)hd * BB * HH);
    }
    k_head_all<<<9, 192, 0, stream>>>(pooled, main_Wf, main_bf, aux_Wf, aux_bf, out);
}

// Round 3
// 1657.308 us; speedup vs baseline: 2.1430x; 1.3863x over previous
//
#include <hip/hip_runtime.h>
#include <hip/hip_bf16.h>
#include <math.h>

#define BB 16
#define TT 360
#define VV 25
#define NN 9000
#define EE 72000
#define HH 128
#define RR (NN * BB)  // 144000 rows, node-major: row = n*BB + b
#define NTILES (RR / 128)  // 1125
#define NCLSS 12
#define EPSB 1e-5f

typedef short short8 __attribute__((ext_vector_type(8)));
typedef float float16v __attribute__((ext_vector_type(16)));
typedef unsigned short ushort_t;

__device__ __forceinline__ float bf2f(ushort_t u) {
    union { unsigned i; float f; } w;
    w.i = ((unsigned)u) << 16;
    return w.f;
}
__device__ __forceinline__ ushort_t f2bf(float f) {
    union { float f; unsigned i; } w;
    w.f = f;
    unsigned r = (w.i + 0x7FFF + ((w.i >> 16) & 1)) >> 16;  // RNE
    return (ushort_t)r;
}

// ---------------- graph preprocessing ----------------

__global__ void k_count(const int* __restrict__ ei, int* __restrict__ counts) {
    int e = blockIdx.x * 256 + threadIdx.x;
    if (e < EE) atomicAdd(&counts[ei[EE + e]], 1);
}

__global__ void k_dinv(const int* __restrict__ counts, float* __restrict__ dinv) {
    int n = blockIdx.x * 256 + threadIdx.x;
    if (n < NN) dinv[n] = rsqrtf((float)(counts[n] + 1));
}

__global__ void k_scan(const int* __restrict__ counts, int* __restrict__ rowptr) {
    __shared__ int part[1024];
    int t = threadIdx.x;
    int base = t * 9;
    int loc[9];
    int s = 0;
#pragma unroll
    for (int i = 0; i < 9; i++) {
        int idx = base + i;
        int v = (idx < NN) ? counts[idx] : 0;
        loc[i] = s;
        s += v;
    }
    part[t] = s;
    __syncthreads();
    for (int d = 1; d < 1024; d <<= 1) {
        int v = (t >= d) ? part[t - d] : 0;
        __syncthreads();
        part[t] += v;
        __syncthreads();
    }
    int excl = (t == 0) ? 0 : part[t - 1];
#pragma unroll
    for (int i = 0; i < 9; i++) {
        int idx = base + i;
        if (idx < NN) rowptr[idx] = excl + loc[i];
    }
    if (t == 1023) rowptr[NN] = part[1023];
}

__global__ void k_fill(const int* __restrict__ ei, const int* __restrict__ rowptr,
                       int* __restrict__ cursor, const float* __restrict__ dinv,
                       int* __restrict__ csr_src, float* __restrict__ csr_coef) {
    int e = blockIdx.x * 256 + threadIdx.x;
    if (e >= EE) return;
    int s = ei[e], d = ei[EE + e];
    int slot = rowptr[d] + atomicAdd(&cursor[d], 1);
    csr_src[slot] = s;
    csr_coef[slot] = dinv[s] * dinv[d];
}

// ---------------- L0 propagation of raw x (2 channels) ----------------
__global__ void k_prop2(const float* __restrict__ x, float* __restrict__ P0,
                        const int* __restrict__ rowptr, const int* __restrict__ csr_src,
                        const float* __restrict__ coef, const float* __restrict__ dinv) {
    int n = blockIdx.x * 256 + threadIdx.x;
    if (n >= NN) return;
    int b = blockIdx.y;
    const float* xb = x + (size_t)b * NN * 2;
    float d2 = dinv[n] * dinv[n];
    float a0 = d2 * xb[2 * n], a1 = d2 * xb[2 * n + 1];
    int beg = rowptr[n], end = rowptr[n + 1];
    for (int j = beg; j < end; j++) {
        int s = csr_src[j];
        float cf = coef[j];
        a0 += cf * xb[2 * s];
        a1 += cf * xb[2 * s + 1];
    }
    float* Pb = P0 + (size_t)(n * BB + b) * 2;
    Pb[0] = a0;
    Pb[1] = a1;
}

// L0 matmul (K=2) with fused BN stats. Grid-stride: 1125 blocks x 8 iters x 256 thr.
__global__ void __launch_bounds__(256) k_mm2(const float* __restrict__ P0,
                                             ushort_t* __restrict__ A,
                                             const float* __restrict__ W,
                                             const float* __restrict__ bias,
                                             float* __restrict__ ssum, float* __restrict__ ssq) {
    __shared__ float L1[256][8], L2[256][8];
    int t = threadIdx.x;
    int cg = t & 15, c8 = cg * 8;
    float wv0[8], wv1[8], bv[8];
#pragma unroll
    for (int j = 0; j < 8; j++) {
        wv0[j] = W[c8 + j];
        wv1[j] = W[HH + c8 + j];
        bv[j] = bias[c8 + j];
    }
    float s1[8], s2[8];
#pragma unroll
    for (int j = 0; j < 8; j++) { s1[j] = 0.f; s2[j] = 0.f; }
    for (int i = blockIdx.x * 256 + t; i < RR * 16; i += gridDim.x * 256) {
        int r = i >> 4;
        float p0 = P0[2 * (size_t)r], p1 = P0[2 * (size_t)r + 1];
        short8 o;
#pragma unroll
        for (int j = 0; j < 8; j++) {
            float v = p0 * wv0[j] + p1 * wv1[j] + bv[j];
            s1[j] += v;
            s2[j] += v * v;
            o[j] = (short)f2bf(v);
        }
        *(short8*)(A + (size_t)r * HH + c8) = o;
    }
#pragma unroll
    for (int j = 0; j < 8; j++) { L1[t][j] = s1[j]; L2[t][j] = s2[j]; }
    __syncthreads();
    if (t < 16) {
#pragma unroll
        for (int g = 1; g < 16; g++)
#pragma unroll
            for (int j = 0; j < 8; j++) {
                s1[j] = (g == 1 ? L1[t][j] : s1[j]) + L1[t + 16 * g][j];
                s2[j] = (g == 1 ? L2[t][j] : s2[j]) + L2[t + 16 * g][j];
            }
#pragma unroll
        for (int j = 0; j < 8; j++) {
            atomicAdd(&ssum[t * 8 + j], s1[j]);
            atomicAdd(&ssq[t * 8 + j], s2[j]);
        }
    }
}

// ---------------- fused BN-affine + ReLU + propagation ----------------
__global__ void __launch_bounds__(256) k_prop(const ushort_t* __restrict__ h,
                                              ushort_t* __restrict__ P,
                                              const int* __restrict__ rowptr,
                                              const int* __restrict__ csr_src,
                                              const float* __restrict__ coef,
                                              const float* __restrict__ dinv,
                                              const float* __restrict__ scale,
                                              const float* __restrict__ shiftv, int shn) {
    int n = blockIdx.x;
    int t = threadIdx.x;
    int b = t >> 4, coff = (t & 15) * 8;
    float sc[8], sh[8];
#pragma unroll
    for (int j = 0; j < 8; j++) {
        sc[j] = scale[coff + j];
        sh[j] = shiftv[coff + j];
    }
    float acc[8];
    int pn = n + shn;
    if (pn >= NN) pn -= NN;
    float d2 = dinv[n] * dinv[n];
    {
        short8 v = *(const short8*)(h + (size_t)(pn * BB + b) * HH + coff);
#pragma unroll
        for (int j = 0; j < 8; j++) {
            float f = bf2f((ushort_t)v[j]) * sc[j] + sh[j];
            acc[j] = d2 * fmaxf(f, 0.f);
        }
    }
    int beg = rowptr[n], end = rowptr[n + 1];
    for (int e = beg; e < end; e++) {
        int s = csr_src[e];
        float cf = coef[e];
        int ps = s + shn;
        if (ps >= NN) ps -= NN;
        short8 v = *(const short8*)(h + (size_t)(ps * BB + b) * HH + coff);
#pragma unroll
        for (int j = 0; j < 8; j++) {
            float f = bf2f((ushort_t)v[j]) * sc[j] + sh[j];
            acc[j] += cf * fmaxf(f, 0.f);
        }
    }
    short8 o;
#pragma unroll
    for (int j = 0; j < 8; j++) o[j] = (short)f2bf(acc[j]);
    *(short8*)(P + (size_t)(n * BB + b) * HH + coff) = o;
}

// ---------------- MFMA matmul + fused BN stats ----------------
// grid-stride over 1125 row-tiles of 128; W^T staged once per block (swizzled).
__global__ void __launch_bounds__(256) k_mfma(const ushort_t* __restrict__ P,
                                              ushort_t* __restrict__ A,
                                              const float* __restrict__ W,
                                              const float* __restrict__ bias,
                                              float* __restrict__ ssum,
                                              float* __restrict__ ssq) {
    __shared__ ushort_t wt[128 * 128];  // 32KB, chunk-XOR-swizzled wt[c][k]
    __shared__ float rb1[4][128], rb2[4][128];  // 4KB stats reduction
    int t = threadIdx.x;
    for (int i = t; i < 16384; i += 256) {
        int k = i & 127, c = i >> 7;
        int chunk = (k >> 3) ^ (c & 15);
        wt[c * 128 + chunk * 8 + (k & 7)] = f2bf(W[(size_t)k * HH + c]);
    }
    __syncthreads();
    int w = t >> 6, l = t & 63;
    int rw = w >> 1;           // row-half of tile
    int cb = (w & 1) * 64;     // col-half
    int lr = l & 31, hi = l >> 5;
    float bv[2] = {bias[cb + lr], bias[cb + 32 + lr]};
    float s1a[2] = {0.f, 0.f}, s2a[2] = {0.f, 0.f};

    for (int tile = blockIdx.x; tile < NTILES; tile += gridDim.x) {
        int r0 = tile * 128 + rw * 64;
        float16v acc[2][2];
#pragma unroll
        for (int rt = 0; rt < 2; rt++)
#pragma unroll
            for (int ct = 0; ct < 2; ct++) acc[rt][ct] = (float16v)(0.0f);
#pragma unroll
        for (int ks = 0; ks < 8; ks++) {
            int koff = ks * 16 + hi * 8;
            short8 a0 = *(const short8*)(P + (size_t)(r0 + lr) * HH + koff);
            short8 a1 = *(const short8*)(P + (size_t)(r0 + 32 + lr) * HH + koff);
#pragma unroll
            for (int ct = 0; ct < 2; ct++) {
                int c = cb + ct * 32 + lr;
                int chunk = (ks * 2 + hi) ^ (c & 15);
                short8 bf = *(const short8*)(wt + c * 128 + chunk * 8);
                acc[0][ct] = __builtin_amdgcn_mfma_f32_32x32x16_bf16(a0, bf, acc[0][ct], 0, 0, 0);
                acc[1][ct] = __builtin_amdgcn_mfma_f32_32x32x16_bf16(a1, bf, acc[1][ct], 0, 0, 0);
            }
        }
#pragma unroll
        for (int rt = 0; rt < 2; rt++)
#pragma unroll
            for (int ct = 0; ct < 2; ct++) {
                int c = cb + ct * 32 + lr;
#pragma unroll
                for (int g = 0; g < 16; g++) {
                    int row = r0 + rt * 32 + (g & 3) + 8 * (g >> 2) + 4 * hi;
                    float v = acc[rt][ct][g] + bv[ct];
                    s1a[ct] += v;
                    s2a[ct] += v * v;
                    A[(size_t)row * HH + c] = f2bf(v);
                }
            }
    }
    int slot = rw * 2 + hi;
#pragma unroll
    for (int ct = 0; ct < 2; ct++) {
        int cidx = cb + ct * 32 + lr;
        rb1[slot][cidx] = s1a[ct];
        rb2[slot][cidx] = s2a[ct];
    }
    __syncthreads();
    if (t < 128) {
        float a1 = rb1[0][t] + rb1[1][t] + rb1[2][t] + rb1[3][t];
        float a2 = rb2[0][t] + rb2[1][t] + rb2[2][t] + rb2[3][t];
        atomicAdd(&ssum[t], a1);
        atomicAdd(&ssq[t], a2);
    }
}

// finalize BN affine; then re-zero ssum/ssq for the next layer's stats
__global__ void k_bnfin(float* __restrict__ ssum, float* __restrict__ ssq,
                        const float* __restrict__ g, const float* __restrict__ be,
                        float* __restrict__ scale, float* __restrict__ shiftv) {
    int c = threadIdx.x;
    float inv = 1.0f / (float)RR;
    float mu = ssum[c] * inv;
    float var = ssq[c] * inv - mu * mu;
    float sc = g[c] * rsqrtf(var + EPSB);
    scale[c] = sc;
    shiftv[c] = be[c] - mu * sc;
    ssum[c] = 0.f;
    ssq[c] = 0.f;
}

// fused BN-affine + ReLU + mean-pool (per head)
__global__ void __launch_bounds__(256) k_relu_pool(const ushort_t* __restrict__ A,
                                                   const float* __restrict__ scale,
                                                   const float* __restrict__ shiftv,
                                                   float* __restrict__ pooled) {
    __shared__ float L[256][8];
    int t = threadIdx.x;
    int b = blockIdx.y;
    int n0 = blockIdx.x * 250;
    int ng = t >> 4, c8 = (t & 15) * 8;
    float sc[8], sh[8];
#pragma unroll
    for (int j = 0; j < 8; j++) {
        sc[j] = scale[c8 + j];
        sh[j] = shiftv[c8 + j];
    }
    float acc[8];
#pragma unroll
    for (int j = 0; j < 8; j++) acc[j] = 0.f;
    for (int n = n0 + ng; n < n0 + 250; n += 16) {
        short8 v = *(const short8*)(A + (size_t)(n * BB + b) * HH + c8);
#pragma unroll
        for (int j = 0; j < 8; j++) {
            float f = bf2f((ushort_t)v[j]) * sc[j] + sh[j];
            acc[j] += fmaxf(f, 0.f);
        }
    }
#pragma unroll
    for (int j = 0; j < 8; j++) L[t][j] = acc[j];
    __syncthreads();
    if (ng == 0) {
#pragma unroll
        for (int g = 1; g < 16; g++)
#pragma unroll
            for (int j = 0; j < 8; j++) acc[j] += L[t + 16 * g][j];
#pragma unroll
        for (int j = 0; j < 8; j++) atomicAdd(&pooled[b * HH + t * 8 + j], acc[j]);
    }
}

// all 9 heads: linear + log_softmax
__global__ void __launch_bounds__(192) k_head_all(const float* __restrict__ pooled,
                                                  const float* __restrict__ main_Wf,
                                                  const float* __restrict__ main_bf,
                                                  const float* __restrict__ aux_Wf,
                                                  const float* __restrict__ aux_bf,
                                                  float* __restrict__ out) {
    int hd = blockIdx.x;
    const float* Wf = hd ? aux_Wf + (size_t)(hd - 1) * HH * NCLSS : main_Wf;
    const float* bf = hd ? aux_bf + (hd - 1) * NCLSS : main_bf;
    const float* pl = pooled + (size_t)hd * BB * HH;
    __shared__ float z[BB][NCLSS];
    __shared__ float lse[BB];
    int t = threadIdx.x;
    int b = t / NCLSS, j = t % NCLSS;
    if (t < BB * NCLSS) {
        float acc = bf[j];
        const float invn = 1.0f / NN;
        for (int c = 0; c < HH; c++) acc += pl[b * HH + c] * invn * Wf[c * NCLSS + j];
        z[b][j] = acc;
    }
    __syncthreads();
    if (t < BB) {
        float m = -1e30f;
        for (int j2 = 0; j2 < NCLSS; j2++) m = fmaxf(m, z[t][j2]);
        float s = 0.f;
        for (int j2 = 0; j2 < NCLSS; j2++) s += expf(z[t][j2] - m);
        lse[t] = m + logf(s);
    }
    __syncthreads();
    if (t < BB * NCLSS) {
        float* o = hd ? out + BB * NCLSS + ((size_t)b * 8 + (hd - 1)) * NCLSS + j
                      : out + b * NCLSS + j;
        *o = z[b][j] - lse[b];
    }
}

// ---------------- host ----------------

extern "C" void kernel_launch(void* const* d_in, const int* in_sizes, int n_in, void* d_out,
                              int out_size, void* d_ws, size_t ws_size, hipStream_t stream) {
    const float* x = (const float*)d_in[0];
    const int* ei = (const int*)d_in[1];
    const float* W_in = (const float*)d_in[2];
    const float* b_in = (const float*)d_in[3];
    const float* g_in = (const float*)d_in[4];
    const float* be_in = (const float*)d_in[5];
    const float* shared_W = (const float*)d_in[6];
    const float* shared_b = (const float*)d_in[7];
    const float* shared_g = (const float*)d_in[8];
    const float* shared_be = (const float*)d_in[9];
    const float* main_Wg = (const float*)d_in[10];
    const float* main_bg = (const float*)d_in[11];
    const float* main_g = (const float*)d_in[12];
    const float* main_be = (const float*)d_in[13];
    const float* main_Wf = (const float*)d_in[14];
    const float* main_bf = (const float*)d_in[15];
    const float* aux_Wg = (const float*)d_in[16];
    const float* aux_bg = (const float*)d_in[17];
    const float* aux_g = (const float*)d_in[18];
    const float* aux_be = (const float*)d_in[19];
    const float* aux_Wf = (const float*)d_in[20];
    const float* aux_bf = (const float*)d_in[21];
    float* out = (float*)d_out;

    char* w = (char*)d_ws;
    const size_t BIG = (size_t)RR * HH * 2;
    ushort_t* U = (ushort_t*)w; w += BIG;
    ushort_t* V = (ushort_t*)w; w += BIG;
    ushort_t* P = (ushort_t*)w; w += BIG;
    float* P0 = (float*)w;      w += (size_t)RR * 2 * 4;
    int* csr_src = (int*)w;     w += EE * 4;
    float* csr_coef = (float*)w; w += EE * 4;
    int* counts = (int*)w;      w += NN * 4;
    int* cursor = (int*)w;      w += NN * 4;
    float* dinv = (float*)w;    w += NN * 4;
    int* rowptr = (int*)w;      w += 36016;
    float* ssum = (float*)w;    w += 512;
    float* ssq = (float*)w;     w += 512;
    float* pooled = (float*)w;  w += 9 * BB * HH * 4;
    float* tscale = (float*)w;  w += 512;
    float* tshift = (float*)w;  w += 512;
    float* hscale = (float*)w;  w += 512;
    float* hshift = (float*)w;  w += 512;

    hipMemsetAsync(counts, 0, 2 * NN * 4, stream);
    hipMemsetAsync(ssum, 0, 512 + 512 + 9 * BB * HH * 4, stream);

    k_count<<<(EE + 255) / 256, 256, 0, stream>>>(ei, counts);
    k_dinv<<<(NN + 255) / 256, 256, 0, stream>>>(counts, dinv);
    k_scan<<<1, 1024, 0, stream>>>(counts, rowptr);
    k_fill<<<(EE + 255) / 256, 256, 0, stream>>>(ei, rowptr, cursor, dinv, csr_src, csr_coef);

    // L0
    {
        dim3 g((NN + 255) / 256, BB);
        k_prop2<<<g, 256, 0, stream>>>(x, P0, rowptr, csr_src, csr_coef, dinv);
        k_mm2<<<1125, 256, 0, stream>>>(P0, U, W_in, b_in, ssum, ssq);
        k_bnfin<<<1, HH, 0, stream>>>(ssum, ssq, g_in, be_in, tscale, tshift);
    }

    // shared trunk layers
    ushort_t* hcur = U;
    ushort_t* hnext = V;
    for (int l = 0; l < 2; l++) {
        k_prop<<<NN, 256, 0, stream>>>(hcur, P, rowptr, csr_src, csr_coef, dinv, tscale, tshift, 0);
        k_mfma<<<563, 256, 0, stream>>>(P, hnext, shared_W + (size_t)l * HH * HH,
                                        shared_b + l * HH, ssum, ssq);
        k_bnfin<<<1, HH, 0, stream>>>(ssum, ssq, shared_g + l * HH, shared_be + l * HH, tscale,
                                      tshift);
        ushort_t* tmp = hcur; hcur = hnext; hnext = tmp;
    }

    // heads
    for (int hd = 0; hd < 9; hd++) {
        int shift = hd * 1000;
        const float* Wg = (hd == 0) ? main_Wg : aux_Wg + (size_t)(hd - 1) * HH * HH;
        const float* bg = (hd == 0) ? main_bg : aux_bg + (hd - 1) * HH;
        const float* gg = (hd == 0) ? main_g : aux_g + (hd - 1) * HH;
        const float* be = (hd == 0) ? main_be : aux_be + (hd - 1) * HH;

        k_prop<<<NN, 256, 0, stream>>>(hcur, P, rowptr, csr_src, csr_coef, dinv, tscale, tshift,
                                       shift);
        k_mfma<<<563, 256, 0, stream>>>(P, hnext, Wg, bg, ssum, ssq);
        k_bnfin<<<1, HH, 0, stream>>>(ssum, ssq, gg, be, hscale, hshift);
        dim3 gp(36, BB);
        k_relu_pool<<<gp, 256, 0, stream>>>(hnext, hscale, hshift, pooled + (size_t)hd * BB * HH);
    }
    k_head_all<<<9, 192, 0, stream>>>(pooled, main_Wf, main_bf, aux_Wf, aux_bf, out);
}